// Round 1
// baseline (508.668 us; speedup 1.0000x reference)
//
#include <hip/hip_runtime.h>

#define BB 4
#define NN 64
#define RR 8
#define DD 32
#define HH 96
#define EE 2
#define NGROUP (BB*NN*RR)   // 2048

// workspace float offsets
#define OFF_WR_R   0                      // nrWr row-major   [b][n][r][h]   196608
#define OFF_WS_T   196608                 // nrWs transposed  [b][r][h][n]   196608
#define OFF_NER0_R 393216                 // ner0 row-major
#define OFF_NES0_T 589824                 // nes0 transposed
#define OFF_NER1_R 786432
#define OFF_NES1_T 983040
#define OFF_ENC    1179648                // node_enc row-major
#define OFF_AGG    1376256                // agg row-major
#define OFF_W20T   1572864                // ep0_W2 transposed (9216)
#define OFF_W21T   1582080                // ep1_W2 transposed (9216)
#define OFF_EE0    1591296                // edge_effect step0, [g][h][j], 12582912 (FULL variant only)
#define WS_FULL_FLOATS (OFF_EE0 + (size_t)NGROUP*HH*NN)

// ---------------------------------------------------------------------------
// K1: node encodings + projections; extra blocks transpose ep*_W2.
// grid: NGROUP + 2*HH blocks of 64
// ---------------------------------------------------------------------------
__global__ __launch_bounds__(64)
void k1_node(const float* __restrict__ node_rep,
             const float* __restrict__ ne_W, const float* __restrict__ ne_b,
             const float* __restrict__ ee_W,
             const float* __restrict__ ep0_W1,
             const float* __restrict__ ep0_W2, const float* __restrict__ ep1_W2,
             float* __restrict__ wr_r, float* __restrict__ ws_t,
             float* __restrict__ ner0_r, float* __restrict__ nes0_t,
             float* __restrict__ enc_out,
             float* __restrict__ w20t, float* __restrict__ w21t)
{
    int blk = blockIdx.x;
    int l = threadIdx.x;
    if (blk >= NGROUP) {                       // weight transpose blocks
        int idx = blk - NGROUP;                // 0..191
        int mat = idx / HH;
        int c = idx % HH;
        const float* W2 = mat ? ep1_W2 : ep0_W2;
        float* Wt = (mat ? w21t : w20t) + c*HH;
        Wt[l] = W2[l*HH + c];
        if (l < 32) Wt[64+l] = W2[(64+l)*HH + c];
        return;
    }
    int b = blk >> 9, n = (blk >> 3) & 63, r = blk & 7;
    __shared__ float sX[DD];
    __shared__ float sEnc[HH];
    const float* x = node_rep + (size_t)blk * DD;
    if (l < DD) sX[l] = x[l];
    __syncthreads();

    float ne0 = ne_b[l], wr0 = 0.f, ws0 = 0.f;
    float ne1 = (l < 32) ? ne_b[64+l] : 0.f, wr1 = 0.f, ws1 = 0.f;
    #pragma unroll 4
    for (int k = 0; k < DD; k++) {
        float xv = sX[k];
        ne0 = fmaf(xv, ne_W[k*HH + l], ne0);
        wr0 = fmaf(xv, ee_W[k*HH + l], wr0);
        ws0 = fmaf(xv, ee_W[(DD+k)*HH + l], ws0);
        if (l < 32) {
            ne1 = fmaf(xv, ne_W[k*HH + 64+l], ne1);
            wr1 = fmaf(xv, ee_W[k*HH + 64+l], wr1);
            ws1 = fmaf(xv, ee_W[(DD+k)*HH + 64+l], ws1);
        }
    }
    ne0 = fmaxf(ne0, 0.f); ne1 = fmaxf(ne1, 0.f);
    float* enc  = enc_out + (size_t)blk*HH;
    float* wrr  = wr_r    + (size_t)blk*HH;
    float* wst  = ws_t    + (size_t)(b*RR + r)*HH*NN;
    enc[l] = ne0; wrr[l] = wr0; wst[l*NN + n] = ws0;
    sEnc[l] = ne0;
    if (l < 32) { enc[64+l] = ne1; wrr[64+l] = wr1; wst[(64+l)*NN + n] = ws1; sEnc[64+l] = ne1; }
    __syncthreads();

    const float* Er0 = ep0_W1;
    const float* Es0 = ep0_W1 + HH*HH;
    float er0 = 0.f, es0 = 0.f, er1 = 0.f, es1 = 0.f;
    #pragma unroll 4
    for (int k = 0; k < HH; k++) {
        float ev = sEnc[k];
        er0 = fmaf(ev, Er0[k*HH + l], er0);
        es0 = fmaf(ev, Es0[k*HH + l], es0);
        if (l < 32) {
            er1 = fmaf(ev, Er0[k*HH + 64+l], er1);
            es1 = fmaf(ev, Es0[k*HH + 64+l], es1);
        }
    }
    float* nerr = ner0_r + (size_t)blk*HH;
    float* nest = nes0_t + (size_t)(b*RR + r)*HH*NN;
    nerr[l] = er0; nest[l*NN + n] = es0;
    if (l < 32) { nerr[64+l] = er1; nest[(64+l)*NN + n] = es1; }
}

// ---------------------------------------------------------------------------
// K2: edge prop step 0 (+ agg reduction, optional ee0 store). wave=(b,i,r), lane=j
// ---------------------------------------------------------------------------
template<bool STORE>
__global__ __launch_bounds__(64)
void k2_edge0(const float* __restrict__ wr_r, const float* __restrict__ ws_t,
              const float* __restrict__ ner_r, const float* __restrict__ nes_t,
              const float* __restrict__ w20t,
              const float* __restrict__ ee_b,
              const float* __restrict__ ep0_W1, const float* __restrict__ ep0_b1,
              const float* __restrict__ ep0_b2,
              float* __restrict__ ee0_out, float* __restrict__ agg_out)
{
    int g = blockIdx.x;            // (b*64+i)*8+r
    int j = threadIdx.x;
    int b = g >> 9, r = g & 7;
    const float* wr  = wr_r  + (size_t)g*HH;                       // uniform
    const float* ner = ner_r + (size_t)g*HH;                       // uniform
    const float* wst = ws_t  + (size_t)(b*RR + r)*HH*NN + j;       // lane, [k*NN]
    const float* nst = nes_t + (size_t)(b*RR + r)*HH*NN + j;
    const float* Ee0 = ep0_W1 + 2*HH*HH;

    float t[HH];
    #pragma unroll
    for (int c = 0; c < HH; c++) t[c] = ep0_b1[c] + ner[c] + nst[c*NN];

    #pragma unroll 4
    for (int k = 0; k < HH; k++) {
        float a = fmaxf(wr[k] + wst[k*NN] + ee_b[k], 0.f);   // edge_enc_k
        const float* wrow = Ee0 + k*HH;
        #pragma unroll
        for (int c = 0; c < HH; c++) t[c] = fmaf(a, wrow[c], t[c]);
    }
    #pragma unroll
    for (int c = 0; c < HH; c++) t[c] = fmaxf(t[c], 0.f);

    float aggA = 0.f, aggB = 0.f;
    float* eo = ee0_out + (size_t)g*HH*NN + j;
    #pragma unroll 2
    for (int c = 0; c < HH; c++) {
        const float* w = w20t + c*HH;
        float a0 = 0.f, a1 = 0.f, a2 = 0.f, a3 = 0.f;
        #pragma unroll
        for (int k = 0; k < HH; k += 4) {
            a0 = fmaf(t[k  ], w[k  ], a0);
            a1 = fmaf(t[k+1], w[k+1], a1);
            a2 = fmaf(t[k+2], w[k+2], a2);
            a3 = fmaf(t[k+3], w[k+3], a3);
        }
        float ee = fmaxf((a0+a1)+(a2+a3) + ep0_b2[c], 0.f);
        if (STORE) eo[c*NN] = ee;
        float s = ee;
        s += __shfl_xor(s, 1);
        s += __shfl_xor(s, 2);
        s += __shfl_xor(s, 4);
        s += __shfl_xor(s, 8);
        s += __shfl_xor(s, 16);
        s += __shfl_xor(s, 32);
        aggA = (c == j)      ? s : aggA;
        aggB = (c == 64 + j) ? s : aggB;
    }
    float* agg = agg_out + (size_t)g*HH;
    agg[j] = aggA;
    if (j < 32) agg[64 + j] = aggB;
}

// ---------------------------------------------------------------------------
// K3: node update after step 0 + step-1 projections. wave=(b,n,r)
// ---------------------------------------------------------------------------
__global__ __launch_bounds__(64)
void k3_node(const float* __restrict__ enc_in, const float* __restrict__ agg_in,
             const float* __restrict__ np_W1, const float* __restrict__ np_b1,
             const float* __restrict__ np_W2, const float* __restrict__ np_b2,
             const float* __restrict__ ep1_W1,
             float* __restrict__ ner1_r, float* __restrict__ nes1_t)
{
    int blk = blockIdx.x, l = threadIdx.x;
    int b = blk >> 9, n = (blk >> 3) & 63, r = blk & 7;
    __shared__ float sEnc[HH], sAgg[HH], sT[HH], sNE[HH];
    const float* enc = enc_in + (size_t)blk*HH;
    const float* agg = agg_in + (size_t)blk*HH;
    sEnc[l] = enc[l]; sAgg[l] = agg[l];
    if (l < 32) { sEnc[64+l] = enc[64+l]; sAgg[64+l] = agg[64+l]; }
    __syncthreads();

    const float* Wn1 = np_W1;
    const float* Wn2 = np_W1 + HH*HH;
    const float* Wn3 = np_W1 + 2*HH*HH;
    float t0 = np_b1[l], t1 = (l < 32) ? np_b1[64+l] : 0.f;
    #pragma unroll 4
    for (int k = 0; k < HH; k++) {
        float ev = sEnc[k], av = sAgg[k];     // node_effect0 == node_enc
        t0 = fmaf(ev, Wn1[k*HH+l], t0);
        t0 = fmaf(ev, Wn2[k*HH+l], t0);
        t0 = fmaf(av, Wn3[k*HH+l], t0);
        if (l < 32) {
            t1 = fmaf(ev, Wn1[k*HH+64+l], t1);
            t1 = fmaf(ev, Wn2[k*HH+64+l], t1);
            t1 = fmaf(av, Wn3[k*HH+64+l], t1);
        }
    }
    sT[l] = fmaxf(t0, 0.f);
    if (l < 32) sT[64+l] = fmaxf(t1, 0.f);
    __syncthreads();

    float e0 = np_b2[l], e1 = (l < 32) ? np_b2[64+l] : 0.f;
    #pragma unroll 4
    for (int k = 0; k < HH; k++) {
        float tv = sT[k];
        e0 = fmaf(tv, np_W2[k*HH+l], e0);
        if (l < 32) e1 = fmaf(tv, np_W2[k*HH+64+l], e1);
    }
    sNE[l] = fmaxf(e0, 0.f);
    if (l < 32) sNE[64+l] = fmaxf(e1, 0.f);
    __syncthreads();

    const float* Er1 = ep1_W1;
    const float* Es1 = ep1_W1 + HH*HH;
    float er0 = 0.f, es0 = 0.f, er1v = 0.f, es1v = 0.f;
    #pragma unroll 4
    for (int k = 0; k < HH; k++) {
        float ev = sNE[k];
        er0 = fmaf(ev, Er1[k*HH+l], er0);
        es0 = fmaf(ev, Es1[k*HH+l], es0);
        if (l < 32) {
            er1v = fmaf(ev, Er1[k*HH+64+l], er1v);
            es1v = fmaf(ev, Es1[k*HH+64+l], es1v);
        }
    }
    float* nerr = ner1_r + (size_t)blk*HH;
    float* nest = nes1_t + (size_t)(b*RR + r)*HH*NN;
    nerr[l] = er0; nest[l*NN + n] = es0;
    if (l < 32) { nerr[64+l] = er1v; nest[(64+l)*NN + n] = es1v; }
}

// ---------------------------------------------------------------------------
// K4: edge prop step 1 fused with prediction head. wave=(b,i,r), lane=j
// FULL: read stored ee0; else recompute it (ws too small).
// ---------------------------------------------------------------------------
template<bool FULL>
__global__ __launch_bounds__(64)
void k4_edge1(const float* __restrict__ wr_r, const float* __restrict__ ws_t,
              const float* __restrict__ ner1_rp, const float* __restrict__ nes1_tp,
              const float* __restrict__ ner0_rp, const float* __restrict__ nes0_tp,
              const float* __restrict__ w20t, const float* __restrict__ w21t,
              const float* __restrict__ ee0_in,
              const float* __restrict__ ee_b,
              const float* __restrict__ ep0_W1, const float* __restrict__ ep0_b1, const float* __restrict__ ep0_b2,
              const float* __restrict__ ep1_W1, const float* __restrict__ ep1_b1, const float* __restrict__ ep1_b2,
              const float* __restrict__ pred_W1, const float* __restrict__ pred_b1,
              const float* __restrict__ pred_W2, const float* __restrict__ pred_b2,
              float* __restrict__ out)
{
    int g = blockIdx.x, j = threadIdx.x;
    int b = g >> 9, i = (g >> 3) & 63, r = g & 7;
    const float* wr   = wr_r    + (size_t)g*HH;
    const float* wst  = ws_t    + (size_t)(b*RR + r)*HH*NN + j;
    const float* ner1 = ner1_rp + (size_t)g*HH;
    const float* nes1 = nes1_tp + (size_t)(b*RR + r)*HH*NN + j;
    const float* Ee1  = ep1_W1 + 2*HH*HH;
    const float* Pe   = pred_W1;
    const float* Pc   = pred_W1 + HH*HH;

    float t1[HH];
    #pragma unroll
    for (int c = 0; c < HH; c++) t1[c] = ep1_b1[c] + ner1[c] + nes1[c*NN];

    if (FULL) {
        const float* e0 = ee0_in + (size_t)g*HH*NN + j;
        #pragma unroll 4
        for (int k = 0; k < HH; k++) {
            float a = e0[k*NN];
            const float* wrow = Ee1 + k*HH;
            #pragma unroll
            for (int c = 0; c < HH; c++) t1[c] = fmaf(a, wrow[c], t1[c]);
        }
    } else {
        float t0[HH];
        const float* ner0 = ner0_rp + (size_t)g*HH;
        const float* nes0 = nes0_tp + (size_t)(b*RR + r)*HH*NN + j;
        const float* Ee0  = ep0_W1 + 2*HH*HH;
        #pragma unroll
        for (int c = 0; c < HH; c++) t0[c] = ep0_b1[c] + ner0[c] + nes0[c*NN];
        #pragma unroll 4
        for (int k = 0; k < HH; k++) {
            float a = fmaxf(wr[k] + wst[k*NN] + ee_b[k], 0.f);
            const float* wrow = Ee0 + k*HH;
            #pragma unroll
            for (int c = 0; c < HH; c++) t0[c] = fmaf(a, wrow[c], t0[c]);
        }
        #pragma unroll
        for (int c = 0; c < HH; c++) t0[c] = fmaxf(t0[c], 0.f);
        #pragma unroll 2
        for (int k = 0; k < HH; k++) {
            const float* w = w20t + k*HH;
            float a0=0.f,a1=0.f,a2=0.f,a3=0.f;
            #pragma unroll
            for (int m = 0; m < HH; m += 4) {
                a0 = fmaf(t0[m  ], w[m  ], a0);
                a1 = fmaf(t0[m+1], w[m+1], a1);
                a2 = fmaf(t0[m+2], w[m+2], a2);
                a3 = fmaf(t0[m+3], w[m+3], a3);
            }
            float ee0k = fmaxf((a0+a1)+(a2+a3) + ep0_b2[k], 0.f);
            const float* wrow = Ee1 + k*HH;
            #pragma unroll
            for (int c = 0; c < HH; c++) t1[c] = fmaf(ee0k, wrow[c], t1[c]);
        }
    }
    #pragma unroll
    for (int c = 0; c < HH; c++) t1[c] = fmaxf(t1[c], 0.f);

    // tp = pred_b1 + edge_enc @ Pc   (recompute edge_enc)
    float tp[HH];
    #pragma unroll
    for (int c = 0; c < HH; c++) tp[c] = pred_b1[c];
    #pragma unroll 4
    for (int k = 0; k < HH; k++) {
        float a = fmaxf(wr[k] + wst[k*NN] + ee_b[k], 0.f);
        const float* wrow = Pc + k*HH;
        #pragma unroll
        for (int c = 0; c < HH; c++) tp[c] = fmaf(a, wrow[c], tp[c]);
    }
    // tp += ee1 @ Pe, ee1_k computed on the fly from t1
    #pragma unroll 2
    for (int k = 0; k < HH; k++) {
        const float* w = w21t + k*HH;
        float a0=0.f,a1=0.f,a2=0.f,a3=0.f;
        #pragma unroll
        for (int m = 0; m < HH; m += 4) {
            a0 = fmaf(t1[m  ], w[m  ], a0);
            a1 = fmaf(t1[m+1], w[m+1], a1);
            a2 = fmaf(t1[m+2], w[m+2], a2);
            a3 = fmaf(t1[m+3], w[m+3], a3);
        }
        float ee1k = fmaxf((a0+a1)+(a2+a3) + ep1_b2[k], 0.f);
        const float* wrow = Pe + k*HH;
        #pragma unroll
        for (int c = 0; c < HH; c++) tp[c] = fmaf(ee1k, wrow[c], tp[c]);
    }
    #pragma unroll
    for (int c = 0; c < HH; c++) tp[c] = fmaxf(tp[c], 0.f);

    float o0 = pred_b2[0], o1 = pred_b2[1];
    #pragma unroll
    for (int c = 0; c < HH; c++) {
        o0 = fmaf(tp[c], pred_W2[c*EE    ], o0);
        o1 = fmaf(tp[c], pred_W2[c*EE + 1], o1);
    }
    float2* out2 = (float2*)out;
    out2[((size_t)(b*NN + i)*NN + j)*RR + r] = make_float2(o0, o1);
}

// ---------------------------------------------------------------------------
extern "C" void kernel_launch(void* const* d_in, const int* in_sizes, int n_in,
                              void* d_out, int out_size, void* d_ws, size_t ws_size,
                              hipStream_t stream)
{
    const float* node_rep = (const float*)d_in[0];
    const float* ne_W    = (const float*)d_in[1];
    const float* ne_b    = (const float*)d_in[2];
    const float* ee_W    = (const float*)d_in[3];
    const float* ee_b    = (const float*)d_in[4];
    const float* np_W1   = (const float*)d_in[5];
    const float* np_b1   = (const float*)d_in[6];
    const float* np_W2   = (const float*)d_in[7];
    const float* np_b2   = (const float*)d_in[8];
    const float* ep0_W1  = (const float*)d_in[9];
    const float* ep0_b1  = (const float*)d_in[10];
    const float* ep0_W2  = (const float*)d_in[11];
    const float* ep0_b2  = (const float*)d_in[12];
    const float* ep1_W1  = (const float*)d_in[13];
    const float* ep1_b1  = (const float*)d_in[14];
    const float* ep1_W2  = (const float*)d_in[15];
    const float* ep1_b2  = (const float*)d_in[16];
    const float* pred_W1 = (const float*)d_in[17];
    const float* pred_b1 = (const float*)d_in[18];
    const float* pred_W2 = (const float*)d_in[19];
    const float* pred_b2 = (const float*)d_in[20];
    float* wsf = (float*)d_ws;
    float* out = (float*)d_out;

    float* wr_r   = wsf + OFF_WR_R;
    float* ws_t   = wsf + OFF_WS_T;
    float* ner0_r = wsf + OFF_NER0_R;
    float* nes0_t = wsf + OFF_NES0_T;
    float* ner1_r = wsf + OFF_NER1_R;
    float* nes1_t = wsf + OFF_NES1_T;
    float* enc    = wsf + OFF_ENC;
    float* agg    = wsf + OFF_AGG;
    float* w20t   = wsf + OFF_W20T;
    float* w21t   = wsf + OFF_W21T;
    float* ee0    = wsf + OFF_EE0;

    bool full = ws_size >= WS_FULL_FLOATS * sizeof(float);

    k1_node<<<NGROUP + 2*HH, 64, 0, stream>>>(node_rep, ne_W, ne_b, ee_W, ep0_W1,
                                              ep0_W2, ep1_W2,
                                              wr_r, ws_t, ner0_r, nes0_t, enc, w20t, w21t);
    if (full)
        k2_edge0<true><<<NGROUP, 64, 0, stream>>>(wr_r, ws_t, ner0_r, nes0_t, w20t,
                                                  ee_b, ep0_W1, ep0_b1, ep0_b2, ee0, agg);
    else
        k2_edge0<false><<<NGROUP, 64, 0, stream>>>(wr_r, ws_t, ner0_r, nes0_t, w20t,
                                                   ee_b, ep0_W1, ep0_b1, ep0_b2, ee0, agg);

    k3_node<<<NGROUP, 64, 0, stream>>>(enc, agg, np_W1, np_b1, np_W2, np_b2,
                                       ep1_W1, ner1_r, nes1_t);

    if (full)
        k4_edge1<true><<<NGROUP, 64, 0, stream>>>(wr_r, ws_t, ner1_r, nes1_t, ner0_r, nes0_t,
                                                  w20t, w21t, ee0, ee_b,
                                                  ep0_W1, ep0_b1, ep0_b2,
                                                  ep1_W1, ep1_b1, ep1_b2,
                                                  pred_W1, pred_b1, pred_W2, pred_b2, out);
    else
        k4_edge1<false><<<NGROUP, 64, 0, stream>>>(wr_r, ws_t, ner1_r, nes1_t, ner0_r, nes0_t,
                                                   w20t, w21t, ee0, ee_b,
                                                   ep0_W1, ep0_b1, ep0_b2,
                                                   ep1_W1, ep1_b1, ep1_b2,
                                                   pred_W1, pred_b1, pred_W2, pred_b2, out);
}